// Round 1
// baseline (694.988 us; speedup 1.0000x reference)
//
#include <hip/hip_runtime.h>
#include <cfloat>

// LabelAwareAttention: B=4096, C=8, S=200, K=64 (all fp32)
//   scores[b,c,s] = <cap[b,c,:], X[b,s,:]>
//   scores masked to -FLT_MAX where capsules_mask[b,c] is True (keep where False)
//   weights = softmax over c
//   out[b,s,k] = sum_c cap[b,c,k] * weights[b,c,s]
//
// Block per b (4096 blocks, 256 threads); thread t handles item s=t (t<200).
// Capsules staged in LDS (2 KB), read back as same-address broadcasts.
// X row held in 16 float4 registers. Memory-bound: ~430 MB total traffic.

#define NB 4096
#define NC 8
#define NS 200
#define NK 64

__global__ __launch_bounds__(256, 4) void laa_kernel(
    const float* __restrict__ cap,   // [B][C][K]
    const int*   __restrict__ mask,  // [B][C] (bool as int32)
    const float* __restrict__ X,     // [B][S][K]
    float*       __restrict__ out)   // [B][S][K]
{
    const int b = blockIdx.x;
    const int t = threadIdx.x;

    __shared__ __align__(16) float cap_lds[NC * NK];  // 2 KB
    __shared__ int mask_lds[NC];

    // Stage capsules: 512 floats with 256 threads -> 2 each (coalesced).
    {
        const float* capb = cap + (size_t)b * (NC * NK);
        cap_lds[t]       = capb[t];
        cap_lds[t + 256] = capb[t + 256];
        if (t < NC) mask_lds[t] = mask[(size_t)b * NC + t];
    }
    __syncthreads();

    if (t >= NS) return;  // no further barriers

    // Load this thread's X row into registers (16 x float4 = 64 floats).
    const float4* xrow = reinterpret_cast<const float4*>(X + ((size_t)b * NS + t) * NK);
    float4 x[NK / 4];
    #pragma unroll
    for (int j = 0; j < NK / 4; ++j) x[j] = xrow[j];

    // Scores: 8 dot products of length 64 (capsule reads are LDS broadcasts).
    float sc[NC];
    #pragma unroll
    for (int c = 0; c < NC; ++c) sc[c] = 0.0f;

    const float4* cap4 = reinterpret_cast<const float4*>(cap_lds);
    #pragma unroll
    for (int j = 0; j < NK / 4; ++j) {
        const float4 xv = x[j];
        #pragma unroll
        for (int c = 0; c < NC; ++c) {
            const float4 cv = cap4[c * (NK / 4) + j];
            sc[c] = fmaf(cv.x, xv.x, sc[c]);
            sc[c] = fmaf(cv.y, xv.y, sc[c]);
            sc[c] = fmaf(cv.z, xv.z, sc[c]);
            sc[c] = fmaf(cv.w, xv.w, sc[c]);
        }
    }

    // Mask (keep where mask is False) + softmax over the 8 capsules.
    // -FLT_MAX matches jnp.finfo(f32).min; all-masked -> exp(0)=1 each -> 1/8.
    float m = -FLT_MAX;
    #pragma unroll
    for (int c = 0; c < NC; ++c) {
        if (mask_lds[c] != 0) sc[c] = -FLT_MAX;
        m = fmaxf(m, sc[c]);
    }
    float w[NC];
    float sum = 0.0f;
    #pragma unroll
    for (int c = 0; c < NC; ++c) {
        w[c] = __expf(sc[c] - m);
        sum += w[c];
    }
    const float inv = 1.0f / sum;  // sum >= 1 (max term is exp(0))
    #pragma unroll
    for (int c = 0; c < NC; ++c) w[c] *= inv;

    // Output: out[s,k] = sum_c cap[c,k] * w[c]; 16 float4 stores.
    float4* orow = reinterpret_cast<float4*>(out + ((size_t)b * NS + t) * NK);
    #pragma unroll
    for (int j = 0; j < NK / 4; ++j) {
        float4 acc = make_float4(0.f, 0.f, 0.f, 0.f);
        #pragma unroll
        for (int c = 0; c < NC; ++c) {
            const float4 cv = cap4[c * (NK / 4) + j];
            acc.x = fmaf(cv.x, w[c], acc.x);
            acc.y = fmaf(cv.y, w[c], acc.y);
            acc.z = fmaf(cv.z, w[c], acc.z);
            acc.w = fmaf(cv.w, w[c], acc.w);
        }
        orow[j] = acc;
    }
}

extern "C" void kernel_launch(void* const* d_in, const int* in_sizes, int n_in,
                              void* d_out, int out_size, void* d_ws, size_t ws_size,
                              hipStream_t stream) {
    const float* cap  = (const float*)d_in[0];  // mlped_capsules [B,C,K] f32
    const int*   mask = (const int*)d_in[1];    // capsules_mask  [B,C]   bool->int32
    const float* X    = (const float*)d_in[2];  // X_item         [B,S,K] f32
    float*       out  = (float*)d_out;          // [B,S,K] f32

    laa_kernel<<<NB, 256, 0, stream>>>(cap, mask, X, out);
}

// Round 2
// 107.423 us; speedup vs baseline: 6.4697x; 6.4697x over previous
//
#include <hip/hip_runtime.h>
#include <cfloat>

// LabelAwareAttention: B=4096, C=8, S=200, K=64 (all fp32)
// Block per b. Phase 0: stage X[b] (51.2 KB) + capsules into LDS with fully
// coalesced float4 global reads. Phase 1: thread-per-row scores + masked
// softmax over C, weights to LDS. Phase 2: (s-group, k-quarter) thread map,
// capsules in registers, fully coalesced float4 stores.
//
// LDS rows padded to 65 words: 65*t mod 32 = t mod 32 -> scalar row accesses
// hit 32 distinct banks (2 lanes each = free).

#define NB 4096
#define NC 8
#define NS 200
#define NK 64
#define NP 65  // padded X row length in words

__global__ __launch_bounds__(256) void laa_kernel(
    const float* __restrict__ cap,   // [B][C][K]
    const int*   __restrict__ mask,  // [B][C]
    const float* __restrict__ X,     // [B][S][K]
    float*       __restrict__ out)   // [B][S][K]
{
    const int b = blockIdx.x;
    const int t = threadIdx.x;

    __shared__ float x_lds[NS * NP];                  // 52.0 KB
    __shared__ __align__(16) float cap_lds[NC * NK];  // 2 KB
    __shared__ float w_lds[NC * NS];                  // 6.4 KB
    __shared__ int   mask_lds[NC];

    const float* Xb   = X   + (size_t)b * (NS * NK);
    const float* capb = cap + (size_t)b * (NC * NK);

    // ---- Phase 0: staging ----
    cap_lds[t]       = capb[t];
    cap_lds[t + 256] = capb[t + 256];
    if (t < NC) mask_lds[t] = mask[(size_t)b * NC + t];

    // X: 3200 float4, lane-consecutive global reads (1 KB/wave-instr),
    // scalar LDS writes into padded layout (conflict-free).
    const float4* X4 = reinterpret_cast<const float4*>(Xb);
    #pragma unroll
    for (int i = 0; i < 13; ++i) {
        const int idx = i * 256 + t;
        if (idx < (NS * NK / 4)) {
            const float4 v = X4[idx];
            const int s = idx >> 4, kq = idx & 15;
            float* dst = &x_lds[s * NP + kq * 4];
            dst[0] = v.x; dst[1] = v.y; dst[2] = v.z; dst[3] = v.w;
        }
    }
    __syncthreads();

    // ---- Phase 1: scores + masked softmax (thread t = item row s) ----
    if (t < NS) {
        const float*  xr   = &x_lds[t * NP];
        const float4* cap4 = reinterpret_cast<const float4*>(cap_lds);
        float sc[NC];
        #pragma unroll
        for (int c = 0; c < NC; ++c) sc[c] = 0.0f;

        #pragma unroll
        for (int j = 0; j < NK / 4; ++j) {
            const float x0 = xr[4 * j + 0], x1 = xr[4 * j + 1];
            const float x2 = xr[4 * j + 2], x3 = xr[4 * j + 3];
            #pragma unroll
            for (int c = 0; c < NC; ++c) {
                const float4 cv = cap4[c * (NK / 4) + j];  // broadcast read
                sc[c] = fmaf(cv.x, x0, sc[c]);
                sc[c] = fmaf(cv.y, x1, sc[c]);
                sc[c] = fmaf(cv.z, x2, sc[c]);
                sc[c] = fmaf(cv.w, x3, sc[c]);
            }
        }

        // mask keeps where false; -FLT_MAX == jnp.finfo(f32).min
        float m = -FLT_MAX;
        #pragma unroll
        for (int c = 0; c < NC; ++c) {
            if (mask_lds[c] != 0) sc[c] = -FLT_MAX;
            m = fmaxf(m, sc[c]);
        }
        float w[NC], sum = 0.0f;
        #pragma unroll
        for (int c = 0; c < NC; ++c) { w[c] = __expf(sc[c] - m); sum += w[c]; }
        const float inv = 1.0f / sum;
        #pragma unroll
        for (int c = 0; c < NC; ++c) w_lds[c * NS + t] = w[c] * inv;
    }
    __syncthreads();

    // ---- Phase 2: outputs, coalesced float4 stores ----
    const int kq = t & 15;   // k quarter (16 B)
    const int g  = t >> 4;   // s sub-group
    const float4* cap4 = reinterpret_cast<const float4*>(cap_lds);
    float4 cr[NC];
    #pragma unroll
    for (int c = 0; c < NC; ++c) cr[c] = cap4[c * (NK / 4) + kq];

    float4* out4 = reinterpret_cast<float4*>(out + (size_t)b * (NS * NK));
    #pragma unroll
    for (int i = 0; i < 13; ++i) {
        const int s = i * 16 + g;
        if (s < NS) {
            float4 acc = make_float4(0.f, 0.f, 0.f, 0.f);
            #pragma unroll
            for (int c = 0; c < NC; ++c) {
                const float wv = w_lds[c * NS + s];  // 16-lane broadcast
                acc.x = fmaf(cr[c].x, wv, acc.x);
                acc.y = fmaf(cr[c].y, wv, acc.y);
                acc.z = fmaf(cr[c].z, wv, acc.z);
                acc.w = fmaf(cr[c].w, wv, acc.w);
            }
            out4[s * (NK / 4) + kq] = acc;  // lanes cover contiguous 1 KB
        }
    }
}

extern "C" void kernel_launch(void* const* d_in, const int* in_sizes, int n_in,
                              void* d_out, int out_size, void* d_ws, size_t ws_size,
                              hipStream_t stream) {
    const float* cap  = (const float*)d_in[0];  // mlped_capsules [B,C,K] f32
    const int*   mask = (const int*)d_in[1];    // capsules_mask  [B,C]
    const float* X    = (const float*)d_in[2];  // X_item         [B,S,K] f32
    float*       out  = (float*)d_out;          // [B,S,K] f32

    laa_kernel<<<NB, 256, 0, stream>>>(cap, mask, X, out);
}

// Round 4
// 93.098 us; speedup vs baseline: 7.4651x; 1.1539x over previous
//
#include <hip/hip_runtime.h>
#include <cfloat>

// LabelAwareAttention: B=4096, C=8, S=200, K=64 (all fp32)
// Thread map: lane = (s, k-quarter). X float4 loads go straight to registers
// (coalesced: idx = it*256 + t is lane-consecutive). Dot-product partials
// reduced across the 16-lane group with DPP butterfly adds (VALU-rate, no DS
// pipe, no barriers). Capsules + mask held in registers after a one-time 2 KB
// LDS stage. Softmax replicated per-lane (8 values, cheap).
//
// R4 fix: tail predicate was idx < NS*(NK/16)=800 (only s<50 written);
// correct bound is NS*(NK/4)=3200 float4s per batch.

#define NB 4096
#define NC 8
#define NS 200
#define NK 64
#define NIT 13       // ceil(3200 / 256)
#define NQ4 (NS * (NK / 4))  // 3200 float4s per b

// x + dpp_perm(x); CTRL: 0xB1=quad xor1, 0x4E=quad xor2,
// 0x141=row_half_mirror (pairs 8-halves), 0x140=row_mirror (pairs 16-halves)
template <int CTRL>
__device__ __forceinline__ float dpp_add(float x) {
    const int xi = __float_as_int(x);
    const int pi = __builtin_amdgcn_update_dpp(xi, xi, CTRL, 0xF, 0xF, true);
    return x + __int_as_float(pi);
}

__global__ __launch_bounds__(256) void laa_kernel(
    const float* __restrict__ cap,   // [B][C][K]
    const int*   __restrict__ mask,  // [B][C]
    const float* __restrict__ X,     // [B][S][K]
    float*       __restrict__ out)   // [B][S][K]
{
    const int b  = blockIdx.x;
    const int t  = threadIdx.x;
    const int kq = t & 15;

    __shared__ __align__(16) float cap_lds[NC * NK];  // 2 KB
    __shared__ int mask_lds[NC];

    const float* capb = cap + (size_t)b * (NC * NK);
    cap_lds[t]       = capb[t];
    cap_lds[t + 256] = capb[t + 256];
    if (t < NC) mask_lds[t] = mask[(size_t)b * NC + t];
    __syncthreads();

    // Per-lane capsule fragments: cr[c] = cap[c][kq*4 .. kq*4+3]
    const float4* cap4 = reinterpret_cast<const float4*>(cap_lds);
    float4 cr[NC];
    #pragma unroll
    for (int c = 0; c < NC; ++c) cr[c] = cap4[c * (NK / 4) + kq];
    int mk[NC];
    #pragma unroll
    for (int c = 0; c < NC; ++c) mk[c] = mask_lds[c];

    const float4* X4 = reinterpret_cast<const float4*>(X + (size_t)b * (NS * NK));
    float4*       O4 = reinterpret_cast<float4*>(out + (size_t)b * (NS * NK));

    for (int it = 0; it < NIT; ++it) {
        const int  idx   = it * 256 + t;  // = s*16 + kq
        const bool valid = idx < NQ4;     // s < 200
        float4 xv = make_float4(0.f, 0.f, 0.f, 0.f);
        if (valid) xv = X4[idx];

        // Partial dots (this lane's 4 k-elements), then 16-lane DPP reduce.
        float sc[NC];
        #pragma unroll
        for (int c = 0; c < NC; ++c) {
            float a;
            a = cr[c].x * xv.x;
            a = fmaf(cr[c].y, xv.y, a);
            a = fmaf(cr[c].z, xv.z, a);
            a = fmaf(cr[c].w, xv.w, a);
            sc[c] = a;
        }
        #pragma unroll
        for (int c = 0; c < NC; ++c) {
            sc[c] = dpp_add<0xB1>(sc[c]);   // + lane^1
            sc[c] = dpp_add<0x4E>(sc[c]);   // + lane^2
            sc[c] = dpp_add<0x141>(sc[c]);  // + across quads (8-group)
            sc[c] = dpp_add<0x140>(sc[c]);  // + across halves (16-group)
        }

        // Masked softmax over the 8 capsules (keep where mask false).
        float m = -FLT_MAX;
        #pragma unroll
        for (int c = 0; c < NC; ++c) {
            if (mk[c] != 0) sc[c] = -FLT_MAX;
            m = fmaxf(m, sc[c]);
        }
        float w[NC], sum = 0.0f;
        #pragma unroll
        for (int c = 0; c < NC; ++c) { w[c] = __expf(sc[c] - m); sum += w[c]; }
        const float inv = 1.0f / sum;

        // out[s, kq*4..] = sum_c cap[c, kq*4..] * w[c]
        float4 acc = make_float4(0.f, 0.f, 0.f, 0.f);
        #pragma unroll
        for (int c = 0; c < NC; ++c) {
            const float wv = w[c] * inv;
            acc.x = fmaf(cr[c].x, wv, acc.x);
            acc.y = fmaf(cr[c].y, wv, acc.y);
            acc.z = fmaf(cr[c].z, wv, acc.z);
            acc.w = fmaf(cr[c].w, wv, acc.w);
        }
        if (valid) O4[idx] = acc;
    }
}

extern "C" void kernel_launch(void* const* d_in, const int* in_sizes, int n_in,
                              void* d_out, int out_size, void* d_ws, size_t ws_size,
                              hipStream_t stream) {
    const float* cap  = (const float*)d_in[0];  // mlped_capsules [B,C,K] f32
    const int*   mask = (const int*)d_in[1];    // capsules_mask  [B,C]
    const float* X    = (const float*)d_in[2];  // X_item         [B,S,K] f32
    float*       out  = (float*)d_out;          // [B,S,K] f32

    laa_kernel<<<NB, 256, 0, stream>>>(cap, mask, X, out);
}

// Round 5
// 86.429 us; speedup vs baseline: 8.0411x; 1.0772x over previous
//
#include <hip/hip_runtime.h>
#include <cfloat>

// LabelAwareAttention: B=4096, C=8, S=200, K=64 (all fp32)
// R5: 8 lanes per item-row (was 16). Lane g=t&7 owns float4s g and g+8 of its
// row -> every X load / out store instruction covers 8 fully-packed 128B
// segments. 8-lane DPP butterfly (xor1, xor2, half-mirror) reduces the dots.
// Softmax instrs now amortize over 8 rows/wave instead of 4, and DPP steps
// drop 4->3. Capsules (2 float4 x 8c = 64 VGPRs) loaded directly from global
// (L3-resident, same-address lanes merge); no LDS, no barriers.

#define NB 4096
#define NC 8
#define NS 200
#define NK 64
#define ROWS_PER_BLK 32          // 256 threads / 8 lanes-per-row
#define NIT 7                    // ceil(200 / 32)

// x + dpp_perm(x); 0xB1=quad xor1, 0x4E=quad xor2, 0x141=row_half_mirror
// (mirrors each 8-lane half: 0<->7,1<->6,2<->5,3<->4 -- crosses the quads)
template <int CTRL>
__device__ __forceinline__ float dpp_add(float x) {
    const int xi = __float_as_int(x);
    const int pi = __builtin_amdgcn_update_dpp(xi, xi, CTRL, 0xF, 0xF, true);
    return x + __int_as_float(pi);
}

__global__ __launch_bounds__(256) void laa_kernel(
    const float* __restrict__ cap,   // [B][C][K]
    const int*   __restrict__ mask,  // [B][C]
    const float* __restrict__ X,     // [B][S][K]
    float*       __restrict__ out)   // [B][S][K]
{
    const int b = blockIdx.x;
    const int t = threadIdx.x;
    const int g = t & 7;   // k-octet lane within the row group
    const int r = t >> 3;  // row slot within block (0..31)

    // Capsule fragments straight from global: cr0[c]=cap[c][g*4e..], cr1 at +8 quads.
    const float4* cap4 = reinterpret_cast<const float4*>(cap + (size_t)b * (NC * NK));
    float4 cr0[NC], cr1[NC];
    #pragma unroll
    for (int c = 0; c < NC; ++c) {
        cr0[c] = cap4[c * (NK / 4) + g];
        cr1[c] = cap4[c * (NK / 4) + g + 8];
    }
    // Mask is block-uniform -> scalar loads.
    const int* maskb = mask + (size_t)b * NC;
    int mk[NC];
    #pragma unroll
    for (int c = 0; c < NC; ++c) mk[c] = maskb[c];

    const float4* X4 = reinterpret_cast<const float4*>(X + (size_t)b * (NS * NK));
    float4*       O4 = reinterpret_cast<float4*>(out + (size_t)b * (NS * NK));

    #pragma unroll 2
    for (int it = 0; it < NIT; ++it) {
        const int  s     = it * ROWS_PER_BLK + r;
        const bool valid = s < NS;  // uniform within each 8-lane group
        float4 xv0 = make_float4(0.f, 0.f, 0.f, 0.f);
        float4 xv1 = xv0;
        if (valid) {
            xv0 = X4[s * (NK / 4) + g];
            xv1 = X4[s * (NK / 4) + g + 8];
        }

        // Partial dots over this lane's 8 k-elements, then 8-lane DPP reduce.
        float sc[NC];
        #pragma unroll
        for (int c = 0; c < NC; ++c) {
            float a;
            a = cr0[c].x * xv0.x;
            a = fmaf(cr0[c].y, xv0.y, a);
            a = fmaf(cr0[c].z, xv0.z, a);
            a = fmaf(cr0[c].w, xv0.w, a);
            a = fmaf(cr1[c].x, xv1.x, a);
            a = fmaf(cr1[c].y, xv1.y, a);
            a = fmaf(cr1[c].z, xv1.z, a);
            a = fmaf(cr1[c].w, xv1.w, a);
            sc[c] = a;
        }
        #pragma unroll
        for (int c = 0; c < NC; ++c) {
            sc[c] = dpp_add<0xB1>(sc[c]);   // + lane^1
            sc[c] = dpp_add<0x4E>(sc[c]);   // + lane^2
            sc[c] = dpp_add<0x141>(sc[c]);  // + other quad of the 8-group
        }

        // Masked softmax over 8 capsules (keep where mask false; -FLT_MAX ==
        // jnp.finfo(f32).min; all-masked -> exp(0) each -> uniform 1/8).
        float m = -FLT_MAX;
        #pragma unroll
        for (int c = 0; c < NC; ++c) {
            if (mk[c] != 0) sc[c] = -FLT_MAX;
            m = fmaxf(m, sc[c]);
        }
        float w[NC], sum = 0.0f;
        #pragma unroll
        for (int c = 0; c < NC; ++c) { w[c] = __expf(sc[c] - m); sum += w[c]; }
        const float inv = 1.0f / sum;

        // out[s, lane's 2 quads] = sum_c cap_frag[c] * w[c]
        float4 a0 = make_float4(0.f, 0.f, 0.f, 0.f);
        float4 a1 = a0;
        #pragma unroll
        for (int c = 0; c < NC; ++c) {
            const float wv = w[c] * inv;
            a0.x = fmaf(cr0[c].x, wv, a0.x);
            a0.y = fmaf(cr0[c].y, wv, a0.y);
            a0.z = fmaf(cr0[c].z, wv, a0.z);
            a0.w = fmaf(cr0[c].w, wv, a0.w);
            a1.x = fmaf(cr1[c].x, wv, a1.x);
            a1.y = fmaf(cr1[c].y, wv, a1.y);
            a1.z = fmaf(cr1[c].z, wv, a1.z);
            a1.w = fmaf(cr1[c].w, wv, a1.w);
        }
        if (valid) {
            O4[s * (NK / 4) + g]     = a0;
            O4[s * (NK / 4) + g + 8] = a1;
        }
    }
}

extern "C" void kernel_launch(void* const* d_in, const int* in_sizes, int n_in,
                              void* d_out, int out_size, void* d_ws, size_t ws_size,
                              hipStream_t stream) {
    const float* cap  = (const float*)d_in[0];  // mlped_capsules [B,C,K] f32
    const int*   mask = (const int*)d_in[1];    // capsules_mask  [B,C]
    const float* X    = (const float*)d_in[2];  // X_item         [B,S,K] f32
    float*       out  = (float*)d_out;          // [B,S,K] f32

    laa_kernel<<<NB, 256, 0, stream>>>(cap, mask, X, out);
}

// Round 6
// 68.873 us; speedup vs baseline: 10.0909x; 1.2549x over previous
//
#include <hip/hip_runtime.h>
#include <cfloat>

// LabelAwareAttention: B=4096, C=8, S=200, K=64 (all fp32)
// R6: R5 structure (8 lanes/row, DPP 8-lane butterfly reduce, caps+mask in
// registers, no LDS/barriers) plus:
//   - depth-1 software pipeline: prefetch iter t+1's X float4s before
//     computing iter t (hides ~500-900cy load latency under ~400cy compute)
//   - non-temporal stores for out: never re-read; skip L2/L3 allocation so
//     the write stream doesn't evict X from Infinity Cache between replays.

#define NB 4096
#define NC 8
#define NS 200
#define NK 64
#define ROWS_PER_BLK 32          // 256 threads / 8 lanes-per-row
#define NIT 7                    // ceil(200 / 32)

// x + dpp_perm(x); 0xB1=quad xor1, 0x4E=quad xor2, 0x141=row_half_mirror
template <int CTRL>
__device__ __forceinline__ float dpp_add(float x) {
    const int xi = __float_as_int(x);
    const int pi = __builtin_amdgcn_update_dpp(xi, xi, CTRL, 0xF, 0xF, true);
    return x + __int_as_float(pi);
}

__device__ __forceinline__ void nt_store4(float4* p, float4 v) {
    __builtin_nontemporal_store(v.x, &p->x);
    __builtin_nontemporal_store(v.y, &p->y);
    __builtin_nontemporal_store(v.z, &p->z);
    __builtin_nontemporal_store(v.w, &p->w);
}

__global__ __launch_bounds__(256) void laa_kernel(
    const float* __restrict__ cap,   // [B][C][K]
    const int*   __restrict__ mask,  // [B][C]
    const float* __restrict__ X,     // [B][S][K]
    float*       __restrict__ out)   // [B][S][K]
{
    const int b = blockIdx.x;
    const int t = threadIdx.x;
    const int g = t & 7;   // k-octet lane within the row group
    const int r = t >> 3;  // row slot within block (0..31)

    // Capsule fragments straight from global (L3-resident, lanes merge).
    const float4* cap4 = reinterpret_cast<const float4*>(cap + (size_t)b * (NC * NK));
    float4 cr0[NC], cr1[NC];
    #pragma unroll
    for (int c = 0; c < NC; ++c) {
        cr0[c] = cap4[c * (NK / 4) + g];
        cr1[c] = cap4[c * (NK / 4) + g + 8];
    }
    const int* maskb = mask + (size_t)b * NC;
    int mk[NC];
    #pragma unroll
    for (int c = 0; c < NC; ++c) mk[c] = maskb[c];

    const float4* X4 = reinterpret_cast<const float4*>(X + (size_t)b * (NS * NK));
    float4*       O4 = reinterpret_cast<float4*>(out + (size_t)b * (NS * NK));

    // Depth-1 pipeline: nxv holds iter t+1's X while iter t computes.
    float4 nxv0 = X4[r * (NK / 4) + g];
    float4 nxv1 = X4[r * (NK / 4) + g + 8];

    #pragma unroll
    for (int it = 0; it < NIT; ++it) {
        const int s = it * ROWS_PER_BLK + r;
        const float4 xv0 = nxv0;
        const float4 xv1 = nxv1;

        // Prefetch next iteration (rows 32..199; last iter has no successor).
        if (it + 1 < NIT) {
            const int sn = (it + 1) * ROWS_PER_BLK + r;
            if (sn < NS) {
                nxv0 = X4[sn * (NK / 4) + g];
                nxv1 = X4[sn * (NK / 4) + g + 8];
            }
        }

        // Partial dots over this lane's 8 k-elements, then 8-lane DPP reduce.
        float sc[NC];
        #pragma unroll
        for (int c = 0; c < NC; ++c) {
            float a;
            a = cr0[c].x * xv0.x;
            a = fmaf(cr0[c].y, xv0.y, a);
            a = fmaf(cr0[c].z, xv0.z, a);
            a = fmaf(cr0[c].w, xv0.w, a);
            a = fmaf(cr1[c].x, xv1.x, a);
            a = fmaf(cr1[c].y, xv1.y, a);
            a = fmaf(cr1[c].z, xv1.z, a);
            a = fmaf(cr1[c].w, xv1.w, a);
            sc[c] = a;
        }
        #pragma unroll
        for (int c = 0; c < NC; ++c) {
            sc[c] = dpp_add<0xB1>(sc[c]);   // + lane^1
            sc[c] = dpp_add<0x4E>(sc[c]);   // + lane^2
            sc[c] = dpp_add<0x141>(sc[c]);  // + other quad of the 8-group
        }

        // Masked softmax over 8 capsules (keep where mask false; -FLT_MAX ==
        // jnp.finfo(f32).min; all-masked -> uniform 1/8).
        float m = -FLT_MAX;
        #pragma unroll
        for (int c = 0; c < NC; ++c) {
            if (mk[c] != 0) sc[c] = -FLT_MAX;
            m = fmaxf(m, sc[c]);
        }
        float w[NC], sum = 0.0f;
        #pragma unroll
        for (int c = 0; c < NC; ++c) { w[c] = __expf(sc[c] - m); sum += w[c]; }
        const float inv = 1.0f / sum;

        // out[s, lane's 2 quads] = sum_c cap_frag[c] * w[c]
        float4 a0 = make_float4(0.f, 0.f, 0.f, 0.f);
        float4 a1 = a0;
        #pragma unroll
        for (int c = 0; c < NC; ++c) {
            const float wv = w[c] * inv;
            a0.x = fmaf(cr0[c].x, wv, a0.x);
            a0.y = fmaf(cr0[c].y, wv, a0.y);
            a0.z = fmaf(cr0[c].z, wv, a0.z);
            a0.w = fmaf(cr0[c].w, wv, a0.w);
            a1.x = fmaf(cr1[c].x, wv, a1.x);
            a1.y = fmaf(cr1[c].y, wv, a1.y);
            a1.z = fmaf(cr1[c].z, wv, a1.z);
            a1.w = fmaf(cr1[c].w, wv, a1.w);
        }
        if (s < NS) {
            nt_store4(&O4[s * (NK / 4) + g],     a0);
            nt_store4(&O4[s * (NK / 4) + g + 8], a1);
        }
    }
}

extern "C" void kernel_launch(void* const* d_in, const int* in_sizes, int n_in,
                              void* d_out, int out_size, void* d_ws, size_t ws_size,
                              hipStream_t stream) {
    const float* cap  = (const float*)d_in[0];  // mlped_capsules [B,C,K] f32
    const int*   mask = (const int*)d_in[1];    // capsules_mask  [B,C]
    const float* X    = (const float*)d_in[2];  // X_item         [B,S,K] f32
    float*       out  = (float*)d_out;          // [B,S,K] f32

    laa_kernel<<<NB, 256, 0, stream>>>(cap, mask, X, out);
}

// Round 7
// 67.650 us; speedup vs baseline: 10.2732x; 1.0181x over previous
//
#include <hip/hip_runtime.h>
#include <cfloat>

// LabelAwareAttention: B=4096, C=8, S=200, K=64 (all fp32)
// R7: R6 structure (8 lanes/row, DPP 8-lane reduce, caps+mask in registers,
// no LDS/barriers, nt stores) with a DEPTH-4 rolling prefetch: 4-slot ring of
// X float4 pairs, iters fully unrolled so ring indices constant-fold into
// fixed VGPRs. 8 outstanding 1KB loads per wave (was 2) to cover ~900cy HBM
// latency at ~2.4 resident waves/SIMD.

#define NB 4096
#define NC 8
#define NS 200
#define NK 64
#define ROWS_PER_BLK 32          // 256 threads / 8 lanes-per-row
#define NIT 7                    // ceil(200 / 32)
#define PF 4                     // prefetch depth (ring slots)

// x + dpp_perm(x); 0xB1=quad xor1, 0x4E=quad xor2, 0x141=row_half_mirror
template <int CTRL>
__device__ __forceinline__ float dpp_add(float x) {
    const int xi = __float_as_int(x);
    const int pi = __builtin_amdgcn_update_dpp(xi, xi, CTRL, 0xF, 0xF, true);
    return x + __int_as_float(pi);
}

__device__ __forceinline__ void nt_store4(float4* p, float4 v) {
    __builtin_nontemporal_store(v.x, &p->x);
    __builtin_nontemporal_store(v.y, &p->y);
    __builtin_nontemporal_store(v.z, &p->z);
    __builtin_nontemporal_store(v.w, &p->w);
}

__global__ __launch_bounds__(256) void laa_kernel(
    const float* __restrict__ cap,   // [B][C][K]
    const int*   __restrict__ mask,  // [B][C]
    const float* __restrict__ X,     // [B][S][K]
    float*       __restrict__ out)   // [B][S][K]
{
    const int b = blockIdx.x;
    const int t = threadIdx.x;
    const int g = t & 7;   // k-octet lane within the row group
    const int r = t >> 3;  // row slot within block (0..31)

    // Capsule fragments straight from global (L3-resident, lanes merge).
    const float4* cap4 = reinterpret_cast<const float4*>(cap + (size_t)b * (NC * NK));
    float4 cr0[NC], cr1[NC];
    #pragma unroll
    for (int c = 0; c < NC; ++c) {
        cr0[c] = cap4[c * (NK / 4) + g];
        cr1[c] = cap4[c * (NK / 4) + g + 8];
    }
    const int* maskb = mask + (size_t)b * NC;
    int mk[NC];
    #pragma unroll
    for (int c = 0; c < NC; ++c) mk[c] = maskb[c];

    const float4* X4 = reinterpret_cast<const float4*>(X + (size_t)b * (NS * NK));
    float4*       O4 = reinterpret_cast<float4*>(out + (size_t)b * (NS * NK));

    // 4-slot ring of (xv0, xv1); indices constant-fold after full unroll.
    float4 xb0[PF], xb1[PF];
    #pragma unroll
    for (int p = 0; p < PF; ++p) {
        const int s = p * ROWS_PER_BLK + r;
        if (s < NS) {
            xb0[p] = X4[s * (NK / 4) + g];
            xb1[p] = X4[s * (NK / 4) + g + 8];
        }
    }

    #pragma unroll
    for (int it = 0; it < NIT; ++it) {
        const int s = it * ROWS_PER_BLK + r;
        const float4 xv0 = xb0[it & (PF - 1)];
        const float4 xv1 = xb1[it & (PF - 1)];

        // Refill the slot we just consumed with iter it+PF.
        if (it + PF < NIT) {
            const int sn = (it + PF) * ROWS_PER_BLK + r;
            if (sn < NS) {
                xb0[it & (PF - 1)] = X4[sn * (NK / 4) + g];
                xb1[it & (PF - 1)] = X4[sn * (NK / 4) + g + 8];
            }
        }

        // Partial dots over this lane's 8 k-elements, then 8-lane DPP reduce.
        float sc[NC];
        #pragma unroll
        for (int c = 0; c < NC; ++c) {
            float a;
            a = cr0[c].x * xv0.x;
            a = fmaf(cr0[c].y, xv0.y, a);
            a = fmaf(cr0[c].z, xv0.z, a);
            a = fmaf(cr0[c].w, xv0.w, a);
            a = fmaf(cr1[c].x, xv1.x, a);
            a = fmaf(cr1[c].y, xv1.y, a);
            a = fmaf(cr1[c].z, xv1.z, a);
            a = fmaf(cr1[c].w, xv1.w, a);
            sc[c] = a;
        }
        #pragma unroll
        for (int c = 0; c < NC; ++c) {
            sc[c] = dpp_add<0xB1>(sc[c]);   // + lane^1
            sc[c] = dpp_add<0x4E>(sc[c]);   // + lane^2
            sc[c] = dpp_add<0x141>(sc[c]);  // + other quad of the 8-group
        }

        // Masked softmax over 8 capsules (keep where mask false; -FLT_MAX ==
        // jnp.finfo(f32).min; all-masked -> uniform 1/8).
        float m = -FLT_MAX;
        #pragma unroll
        for (int c = 0; c < NC; ++c) {
            if (mk[c] != 0) sc[c] = -FLT_MAX;
            m = fmaxf(m, sc[c]);
        }
        float w[NC], sum = 0.0f;
        #pragma unroll
        for (int c = 0; c < NC; ++c) { w[c] = __expf(sc[c] - m); sum += w[c]; }
        const float inv = 1.0f / sum;

        // out[s, lane's 2 quads] = sum_c cap_frag[c] * w[c]
        float4 a0 = make_float4(0.f, 0.f, 0.f, 0.f);
        float4 a1 = a0;
        #pragma unroll
        for (int c = 0; c < NC; ++c) {
            const float wv = w[c] * inv;
            a0.x = fmaf(cr0[c].x, wv, a0.x);
            a0.y = fmaf(cr0[c].y, wv, a0.y);
            a0.z = fmaf(cr0[c].z, wv, a0.z);
            a0.w = fmaf(cr0[c].w, wv, a0.w);
            a1.x = fmaf(cr1[c].x, wv, a1.x);
            a1.y = fmaf(cr1[c].y, wv, a1.y);
            a1.z = fmaf(cr1[c].z, wv, a1.z);
            a1.w = fmaf(cr1[c].w, wv, a1.w);
        }
        if (s < NS) {
            nt_store4(&O4[s * (NK / 4) + g],     a0);
            nt_store4(&O4[s * (NK / 4) + g + 8], a1);
        }
    }
}

extern "C" void kernel_launch(void* const* d_in, const int* in_sizes, int n_in,
                              void* d_out, int out_size, void* d_ws, size_t ws_size,
                              hipStream_t stream) {
    const float* cap  = (const float*)d_in[0];  // mlped_capsules [B,C,K] f32
    const int*   mask = (const int*)d_in[1];    // capsules_mask  [B,C]
    const float* X    = (const float*)d_in[2];  // X_item         [B,S,K] f32
    float*       out  = (float*)d_out;          // [B,S,K] f32

    laa_kernel<<<NB, 256, 0, stream>>>(cap, mask, X, out);
}